// Round 1
// baseline (916.412 us; speedup 1.0000x reference)
//
#include <hip/hip_runtime.h>
#include <math.h>

#define S 512
#define W 64
#define MODES 16
#define PAIRS 130816  // 512*511/2
#define INV_SQRT_N 0.04419417382415922f  // 1/sqrt(512)
#define TWO_PI_OVER_N 0.012271846303085130f  // 2*pi/512

// ---------------- fc0: h[b,c,t] = x[b,t,0]*w[0,c] + x[b,t,1]*w[1,c] + bias[c]
__global__ __launch_bounds__(256) void k_fc0(const float* __restrict__ x,
                                             const float* __restrict__ w,
                                             const float* __restrict__ bias,
                                             float* __restrict__ h) {
    int b = blockIdx.x >> 6, c = blockIdx.x & 63;
    int tid = threadIdx.x;
    float w0 = w[c], w1 = w[64 + c], bb = bias[c];
    for (int t = tid; t < S; t += 256) {
        float x0 = x[(b * S + t) * 2];
        float x1 = x[(b * S + t) * 2 + 1];
        h[(b * W + c) * S + t] = x0 * w0 + x1 * w1 + bb;
    }
}

// ---------------- rfft (ortho), first 16 modes only. block=(b,c), 256 thr.
__global__ __launch_bounds__(256) void k_fft(const float* __restrict__ h,
                                             float* __restrict__ Xf) {
    int b = blockIdx.x >> 6, ch = blockIdx.x & 63;
    int tid = threadIdx.x;  // t = tid and tid+256
    const float* hp = h + (b * W + ch) * S;
    float v0 = hp[tid], v1 = hp[tid + 256];
    float re[MODES], im[MODES];
#pragma unroll
    for (int m = 0; m < MODES; ++m) {
        float sn, cs;
        sincosf(TWO_PI_OVER_N * (float)(m * tid), &sn, &cs);
        float a = (m & 1) ? (v0 - v1) : (v0 + v1);  // e^{-i pi m} = (-1)^m
        re[m] = a * cs;
        im[m] = -a * sn;
    }
    __shared__ float part[4][32];
    int lane = tid & 63, wv = tid >> 6;
#pragma unroll
    for (int m = 0; m < MODES; ++m) {
        float r = re[m], ii = im[m];
        for (int off = 32; off; off >>= 1) {
            r += __shfl_down(r, off);
            ii += __shfl_down(ii, off);
        }
        if (lane == 0) { part[wv][2 * m] = r; part[wv][2 * m + 1] = ii; }
    }
    __syncthreads();
    if (tid < 32) {
        float s = part[0][tid] + part[1][tid] + part[2][tid] + part[3][tid];
        Xf[(b * W + ch) * 32 + tid] = s * INV_SQRT_N;
    }
}

// ---------------- complex channel mix: Y[b,o,m] = sum_i Xf[b,i,m]*wm[i,o,m]
__global__ __launch_bounds__(256) void k_mix(const float* __restrict__ Xf,
                                             const float* __restrict__ specw,
                                             float* __restrict__ Y, int l) {
    int idx = blockIdx.x * 256 + threadIdx.x;  // 0..2047
    int b = idx >> 10, o = (idx >> 4) & 63, m = idx & 15;
    float ar = 0.f, ai = 0.f;
    for (int i = 0; i < W; ++i) {
        float xr = Xf[(b * W + i) * 32 + 2 * m];
        float xi = Xf[(b * W + i) * 32 + 2 * m + 1];
        const float* wp = specw + (size_t)((((l * W + i) * W + o) * MODES + m)) * 2;
        float wr = wp[0], wi = wp[1];
        ar += xr * wr - xi * wi;
        ai += xr * wi + xi * wr;
    }
    Y[(b * W + o) * 32 + 2 * m] = ar;
    Y[(b * W + o) * 32 + 2 * m + 1] = ai;
}

// ---------------- irfft (ortho, 16 modes, imag of DC dropped) -> aT[b,t,o]
__global__ __launch_bounds__(256) void k_irfft(const float* __restrict__ Y,
                                               float* __restrict__ aT) {
    int blk = blockIdx.x;
    int b = blk >> 3, t0 = (blk & 7) * 64;
    int tid = threadIdx.x;
    int o = tid & 63, tg = tid >> 6;  // t = t0 + tg + 4*tt
    __shared__ float Ys[2048];
    for (int idx = tid; idx < 2048; idx += 256) Ys[idx] = Y[b * 2048 + idx];
    __syncthreads();
    float yr[MODES], yi[MODES];
#pragma unroll
    for (int m = 0; m < MODES; ++m) {
        yr[m] = Ys[o * 32 + 2 * m];
        yi[m] = Ys[o * 32 + 2 * m + 1];
    }
    float cc[MODES], ss[MODES], cd[MODES], sd[MODES];
#pragma unroll
    for (int m = 1; m < MODES; ++m) {
        sincosf(TWO_PI_OVER_N * (float)(m * (t0 + tg)), &ss[m], &cc[m]);
        sincosf(TWO_PI_OVER_N * (float)(4 * m), &sd[m], &cd[m]);
    }
    for (int tt = 0; tt < 16; ++tt) {
        int t = t0 + tg + 4 * tt;
        float acc = yr[0];
#pragma unroll
        for (int m = 1; m < MODES; ++m) {
            acc += 2.0f * (yr[m] * cc[m] - yi[m] * ss[m]);
            float nc = cc[m] * cd[m] - ss[m] * sd[m];
            float ns = ss[m] * cd[m] + cc[m] * sd[m];
            cc[m] = nc; ss[m] = ns;
        }
        aT[(b * S + t) * W + o] = acc * INV_SQRT_N;
    }
}

// ---------------- pointwise conv: pT[b,t,o] = sum_i w[o,i]*h[b,i,t] + bias[o]
__global__ __launch_bounds__(256) void k_conv(const float* __restrict__ h,
                                              const float* __restrict__ convw,
                                              const float* __restrict__ convb,
                                              float* __restrict__ pT,
                                              unsigned* __restrict__ vmax, int l) {
    int blk = blockIdx.x;
    int b = blk >> 4, t0 = (blk & 15) * 32;
    int tid = threadIdx.x;
    int o = tid & 63, tg = tid >> 6;
    if (blk == 0 && tid < 2) vmax[tid] = 0u;  // zero v_r_max for this layer
    __shared__ float hs[64 * 33];
    __shared__ float wsh[64 * 65];
    for (int idx = tid; idx < 2048; idx += 256) {
        int r = idx >> 5, t = idx & 31;
        hs[r * 33 + t] = h[(b * W + r) * S + t0 + t];
    }
    for (int idx = tid; idx < 4096; idx += 256) {
        wsh[(idx >> 6) * 65 + (idx & 63)] = convw[l * 4096 + idx];
    }
    __syncthreads();
    float wreg[64];
#pragma unroll
    for (int i = 0; i < W; ++i) wreg[i] = wsh[o * 65 + i];
    float bias = convb[l * W + o];
    for (int tt = 0; tt < 8; ++tt) {
        int tl = tg * 8 + tt;
        float acc = bias;
#pragma unroll
        for (int i = 0; i < W; ++i) acc = fmaf(wreg[i], hs[i * 33 + tl], acc);
        pT[(b * S + t0 + tl) * W + o] = acc;
    }
}

// ---------------- pairwise: v_r[b,j,i], u_x[b,j,i]=exp(-x_r), atomicMax v_r_max
__global__ __launch_bounds__(256) void k_pair(const float* __restrict__ pT,
                                              const float* __restrict__ aT,
                                              float* __restrict__ vr,
                                              float* __restrict__ uxm,
                                              unsigned* __restrict__ vmax) {
    int blk = blockIdx.x;
    int b = blk >> 8;
    int rest = blk & 255;
    int i0 = (rest & 15) * 32, j0 = (rest >> 4) * 32;
    int tid = threadIdx.x;
    int tx = tid & 15, ty = tid >> 4;  // thread covers i=i0+2tx+{0,1}, j=j0+2ty+{0,1}
    __shared__ float Pi[64 * 33], Pj[64 * 33], Vi[64 * 33], Vj[64 * 33];
    for (int idx = tid; idx < 2048; idx += 256) {
        int k = idx >> 6, c = idx & 63;
        Pi[c * 33 + k] = pT[(b * S + i0 + k) * W + c];
        Pj[c * 33 + k] = pT[(b * S + j0 + k) * W + c];
        Vi[c * 33 + k] = aT[(b * S + i0 + k) * W + c];
        Vj[c * 33 + k] = aT[(b * S + j0 + k) * W + c];
    }
    __syncthreads();
    float ax[2][2] = {{0.f, 0.f}, {0.f, 0.f}};
    float av[2][2] = {{0.f, 0.f}, {0.f, 0.f}};
    for (int c = 0; c < W; ++c) {
        float pi0 = Pi[c * 33 + 2 * tx], pi1 = Pi[c * 33 + 2 * tx + 1];
        float pj0 = Pj[c * 33 + 2 * ty], pj1 = Pj[c * 33 + 2 * ty + 1];
        float vi0 = Vi[c * 33 + 2 * tx], vi1 = Vi[c * 33 + 2 * tx + 1];
        float vj0 = Vj[c * 33 + 2 * ty], vj1 = Vj[c * 33 + 2 * ty + 1];
        float d;
        d = pi0 - pj0; ax[0][0] = fmaf(d, d, ax[0][0]);
        d = pi1 - pj0; ax[1][0] = fmaf(d, d, ax[1][0]);
        d = pi0 - pj1; ax[0][1] = fmaf(d, d, ax[0][1]);
        d = pi1 - pj1; ax[1][1] = fmaf(d, d, ax[1][1]);
        d = vi0 - vj0; av[0][0] = fmaf(d, d, av[0][0]);
        d = vi1 - vj0; av[1][0] = fmaf(d, d, av[1][0]);
        d = vi0 - vj1; av[0][1] = fmaf(d, d, av[0][1]);
        d = vi1 - vj1; av[1][1] = fmaf(d, d, av[1][1]);
    }
    float mx = 0.f;
#pragma unroll
    for (int jj = 0; jj < 2; ++jj) {
#pragma unroll
        for (int ii = 0; ii < 2; ++ii) {
            int i = i0 + 2 * tx + ii, j = j0 + 2 * ty + jj;
            float xr = sqrtf(ax[ii][jj]);
            float vv = sqrtf(av[ii][jj]);
            vr[((size_t)b * S + j) * S + i] = vv;
            uxm[((size_t)b * S + j) * S + i] = expf(-xr);
            mx = fmaxf(mx, vv);
        }
    }
    for (int off = 32; off; off >>= 1) mx = fmaxf(mx, __shfl_xor(mx, off));
    if ((tid & 63) == 0) atomicMax(&vmax[b], __float_as_uint(mx));
}

// ---------------- dsmc gather: one wave per (b, j)
__global__ __launch_bounds__(64) void k_dsmc(const float* __restrict__ pT,
                                             const float* __restrict__ aT,
                                             const float* __restrict__ vr,
                                             const float* __restrict__ uxm,
                                             const unsigned* __restrict__ vmaxu,
                                             const float* __restrict__ vecs,
                                             float* __restrict__ h_std,
                                             float* __restrict__ hT,
                                             int l, int do_relu) {
    int b = blockIdx.x >> 9;
    int j = blockIdx.x & 511;
    int c = threadIdx.x;  // 0..63
    __shared__ float vrow[S];
    __shared__ float urow[S];
    const float* vrp = vr + ((size_t)b * S + j) * S;
    const float* uxp = uxm + ((size_t)b * S + j) * S;
    for (int idx = c; idx < S; idx += 64) {
        vrow[idx] = vrp[idx];
        urow[idx] = uxp[idx];
    }
    __syncthreads();
    float vmax = __uint_as_float(vmaxu[b]);
    unsigned long long masks[8];
    int cnt = 0;
#pragma unroll
    for (int k = 0; k < 8; ++k) {
        int i = k * 64 + c;
        float mval = vrow[i] / vmax * urow[i];
        bool f = mval > 0.1f;
        masks[k] = __ballot(f);
        cnt += (int)__popcll(masks[k]);
    }
    float xj = pT[(b * S + j) * W + c];
    float vj = aT[(b * S + j) * W + c];
    float accv = 0.f, accx = 0.f;
    const float* rvp = vecs + ((size_t)(l * 2 + b) * W + c) * PAIRS;
    for (int k = 0; k < 8; ++k) {
        unsigned long long mm = masks[k];
        while (mm) {
            int sb = __builtin_ctzll(mm);
            mm &= mm - 1;
            int i = k * 64 + sb;
            float vi = aT[(b * S + i) * W + c];
            float xi = pT[(b * S + i) * W + c];
            float vrv = vrow[i];
            int lo = (i < j) ? i : j;
            int hi = (i < j) ? j : i;
            int pp = lo * 511 - ((lo * (lo - 1)) >> 1) + (hi - lo - 1);
            float rv = rvp[pp];
            float sgn = (i < j) ? 1.0f : -1.0f;
            accv += (vi + vj) * 0.5f + sgn * (vrv * rv) - vi;
            accx += (xi + xj) * 0.5f;
        }
    }
    float vnew = vj + accv;
    float xnew = (xj + accx) / (float)(cnt + 1) + vnew;
    if (do_relu) xnew = fmaxf(xnew, 0.0f);
    hT[(b * S + j) * W + c] = xnew;
    h_std[(b * W + c) * S + j] = xnew;
}

// ---------------- head: out[b,t] = relu(hT[b,t,:]@fc1 + b1) @ fc2 + b2
__global__ __launch_bounds__(128) void k_head(const float* __restrict__ hT,
                                              const float* __restrict__ fc1w,
                                              const float* __restrict__ fc1b,
                                              const float* __restrict__ fc2w,
                                              const float* __restrict__ fc2b,
                                              float* __restrict__ out) {
    int blk = blockIdx.x;
    int b = blk >> 9, t = blk & 511;
    int k = threadIdx.x;  // 0..127
    __shared__ float hsh[64];
    __shared__ float red[2];
    if (k < 64) hsh[k] = hT[(b * S + t) * W + k];
    __syncthreads();
    float acc = fc1b[k];
#pragma unroll
    for (int c = 0; c < W; ++c) acc = fmaf(hsh[c], fc1w[c * 128 + k], acc);
    acc = fmaxf(acc, 0.f);
    float p = acc * fc2w[k];
    for (int off = 32; off; off >>= 1) p += __shfl_down(p, off);
    int lane = k & 63, wv = k >> 6;
    if (lane == 0) red[wv] = p;
    __syncthreads();
    if (k == 0) out[b * S + t] = red[0] + red[1] + fc2b[0];
}

extern "C" void kernel_launch(void* const* d_in, const int* in_sizes, int n_in,
                              void* d_out, int out_size, void* d_ws, size_t ws_size,
                              hipStream_t stream) {
    const float* x = (const float*)d_in[0];
    // d_in[1] (v) is unused by the reference computation
    const float* vecs = (const float*)d_in[2];
    const float* fc0w = (const float*)d_in[3];
    const float* fc0b = (const float*)d_in[4];
    const float* specw = (const float*)d_in[5];
    const float* convw = (const float*)d_in[6];
    const float* convb = (const float*)d_in[7];
    const float* fc1w = (const float*)d_in[8];
    const float* fc1b = (const float*)d_in[9];
    const float* fc2w = (const float*)d_in[10];
    const float* fc2b = (const float*)d_in[11];
    float* out = (float*)d_out;

    char* ws = (char*)d_ws;
    unsigned* vmax = (unsigned*)ws;                   // 2 x u32 (float bits)
    float* h_std = (float*)(ws + 256);                // 2*64*512
    float* hT = h_std + 65536;                        // 2*512*64
    float* aT = hT + 65536;                           // 2*512*64
    float* pT = aT + 65536;                           // 2*512*64
    float* Xf = pT + 65536;                           // 2*64*16*2
    float* Yb = Xf + 4096;                            // 2*64*16*2
    float* vrbuf = Yb + 4096;                         // 2*512*512
    float* uxbuf = vrbuf + 524288;                    // 2*512*512

    k_fc0<<<128, 256, 0, stream>>>(x, fc0w, fc0b, h_std);
    for (int l = 0; l < 4; ++l) {
        k_fft<<<128, 256, 0, stream>>>(h_std, Xf);
        k_mix<<<8, 256, 0, stream>>>(Xf, specw, Yb, l);
        k_irfft<<<16, 256, 0, stream>>>(Yb, aT);
        k_conv<<<32, 256, 0, stream>>>(h_std, convw, convb, pT, vmax, l);
        k_pair<<<512, 256, 0, stream>>>(pT, aT, vrbuf, uxbuf, vmax);
        k_dsmc<<<1024, 64, 0, stream>>>(pT, aT, vrbuf, uxbuf, vmax, vecs,
                                        h_std, hT, l, (l < 3) ? 1 : 0);
    }
    k_head<<<1024, 128, 0, stream>>>(hT, fc1w, fc1b, fc2w, fc2b, out);
}

// Round 2
// 770.155 us; speedup vs baseline: 1.1899x; 1.1899x over previous
//
#include <hip/hip_runtime.h>
#include <math.h>

#define S 512
#define W 64
#define MODES 16
#define PAIRS 130816  // 512*511/2
#define INV_SQRT_N 0.04419417382415922f  // 1/sqrt(512)
#define TWO_PI_OVER_N 0.012271846303085130f  // 2*pi/512

// ---------------- fc0: h[b,c,t] = x[b,t,0]*w[0,c] + x[b,t,1]*w[1,c] + bias[c]
__global__ __launch_bounds__(256) void k_fc0(const float* __restrict__ x,
                                             const float* __restrict__ w,
                                             const float* __restrict__ bias,
                                             float* __restrict__ h) {
    int b = blockIdx.x >> 6, c = blockIdx.x & 63;
    int tid = threadIdx.x;
    float w0 = w[c], w1 = w[64 + c], bb = bias[c];
    for (int t = tid; t < S; t += 256) {
        float x0 = x[(b * S + t) * 2];
        float x1 = x[(b * S + t) * 2 + 1];
        h[(b * W + c) * S + t] = x0 * w0 + x1 * w1 + bb;
    }
}

// ---------------- rfft (ortho), first 16 modes only. block=(b,c), 256 thr.
__global__ __launch_bounds__(256) void k_fft(const float* __restrict__ h,
                                             float* __restrict__ Xf) {
    int b = blockIdx.x >> 6, ch = blockIdx.x & 63;
    int tid = threadIdx.x;  // t = tid and tid+256
    const float* hp = h + (b * W + ch) * S;
    float v0 = hp[tid], v1 = hp[tid + 256];
    float re[MODES], im[MODES];
#pragma unroll
    for (int m = 0; m < MODES; ++m) {
        float sn, cs;
        sincosf(TWO_PI_OVER_N * (float)(m * tid), &sn, &cs);
        float a = (m & 1) ? (v0 - v1) : (v0 + v1);  // e^{-i pi m} = (-1)^m
        re[m] = a * cs;
        im[m] = -a * sn;
    }
    __shared__ float part[4][32];
    int lane = tid & 63, wv = tid >> 6;
#pragma unroll
    for (int m = 0; m < MODES; ++m) {
        float r = re[m], ii = im[m];
        for (int off = 32; off; off >>= 1) {
            r += __shfl_down(r, off);
            ii += __shfl_down(ii, off);
        }
        if (lane == 0) { part[wv][2 * m] = r; part[wv][2 * m + 1] = ii; }
    }
    __syncthreads();
    if (tid < 32) {
        float s = part[0][tid] + part[1][tid] + part[2][tid] + part[3][tid];
        Xf[(b * W + ch) * 32 + tid] = s * INV_SQRT_N;
    }
}

// ---------------- complex channel mix: Y[b,o,m] = sum_i Xf[b,i,m]*wm[i,o,m]
// block per (b,o): 256 thr = (ip 0..15) x (m 0..15)
__global__ __launch_bounds__(256) void k_mix(const float* __restrict__ Xf,
                                             const float* __restrict__ specw,
                                             float* __restrict__ Y, int l) {
    int b = blockIdx.x >> 6, o = blockIdx.x & 63;
    int tid = threadIdx.x, m = tid & 15, ip = tid >> 4;
    __shared__ float Xs[2048];
    for (int idx = tid; idx < 2048; idx += 256) Xs[idx] = Xf[b * 2048 + idx];
    __syncthreads();
    float ar = 0.f, ai = 0.f;
#pragma unroll
    for (int q = 0; q < 4; ++q) {
        int i = ip * 4 + q;
        const float* wp = specw + (size_t)(((l * W + i) * W + o) * MODES + m) * 2;
        float wr = wp[0], wi = wp[1];
        float xr = Xs[i * 32 + 2 * m], xi = Xs[i * 32 + 2 * m + 1];
        ar += xr * wr - xi * wi;
        ai += xr * wi + xi * wr;
    }
    __shared__ float redr[16][17], redi[16][17];
    redr[ip][m] = ar; redi[ip][m] = ai;
    __syncthreads();
    if (tid < 16) {
        float sr = 0.f, si = 0.f;
        for (int p = 0; p < 16; ++p) { sr += redr[p][tid]; si += redi[p][tid]; }
        Y[(b * W + o) * 32 + 2 * tid] = sr;
        Y[(b * W + o) * 32 + 2 * tid + 1] = si;
    }
}

// ---------------- irfft (ortho, 16 modes, imag of DC dropped) -> aT[b,t,o]
__global__ __launch_bounds__(256) void k_irfft(const float* __restrict__ Y,
                                               float* __restrict__ aT) {
    int blk = blockIdx.x;
    int b = blk >> 4, t0 = (blk & 15) * 32;
    int tid = threadIdx.x;
    int o = tid & 63, tg = tid >> 6;  // t = t0 + tg + 4*tt, tt in 0..7
    __shared__ float Ys[2048];
    for (int idx = tid; idx < 2048; idx += 256) Ys[idx] = Y[b * 2048 + idx];
    __syncthreads();
    float yr[MODES], yi[MODES];
#pragma unroll
    for (int m = 0; m < MODES; ++m) {
        yr[m] = Ys[o * 32 + 2 * m];
        yi[m] = Ys[o * 32 + 2 * m + 1];
    }
    float cc[MODES], ss[MODES], cd[MODES], sd[MODES];
#pragma unroll
    for (int m = 1; m < MODES; ++m) {
        sincosf(TWO_PI_OVER_N * (float)(m * (t0 + tg)), &ss[m], &cc[m]);
        sincosf(TWO_PI_OVER_N * (float)(4 * m), &sd[m], &cd[m]);
    }
    for (int tt = 0; tt < 8; ++tt) {
        int t = t0 + tg + 4 * tt;
        float acc = yr[0];
#pragma unroll
        for (int m = 1; m < MODES; ++m) {
            acc += 2.0f * (yr[m] * cc[m] - yi[m] * ss[m]);
            float nc = cc[m] * cd[m] - ss[m] * sd[m];
            float ns = ss[m] * cd[m] + cc[m] * sd[m];
            cc[m] = nc; ss[m] = ns;
        }
        aT[(b * S + t) * W + o] = acc * INV_SQRT_N;
    }
}

// ---------------- pointwise conv: pT[b,t,o] = sum_i w[o,i]*h[b,i,t] + bias[o]
__global__ __launch_bounds__(256) void k_conv(const float* __restrict__ h,
                                              const float* __restrict__ convw,
                                              const float* __restrict__ convb,
                                              float* __restrict__ pT,
                                              unsigned* __restrict__ vmax, int l) {
    int blk = blockIdx.x;
    int b = blk >> 4, t0 = (blk & 15) * 32;
    int tid = threadIdx.x;
    int o = tid & 63, tg = tid >> 6;
    if (blk == 0 && tid < 2) vmax[tid] = 0u;  // zero v_r_max for this layer
    __shared__ float hs[64 * 33];
    __shared__ float wsh[64 * 65];
    for (int idx = tid; idx < 2048; idx += 256) {
        int r = idx >> 5, t = idx & 31;
        hs[r * 33 + t] = h[(b * W + r) * S + t0 + t];
    }
    for (int idx = tid; idx < 4096; idx += 256) {
        wsh[(idx >> 6) * 65 + (idx & 63)] = convw[l * 4096 + idx];
    }
    __syncthreads();
    float wreg[64];
#pragma unroll
    for (int i = 0; i < W; ++i) wreg[i] = wsh[o * 65 + i];
    float bias = convb[l * W + o];
    for (int tt = 0; tt < 8; ++tt) {
        int tl = tg * 8 + tt;
        float acc = bias;
#pragma unroll
        for (int i = 0; i < W; ++i) acc = fmaf(wreg[i], hs[i * 33 + tl], acc);
        pT[(b * S + t0 + tl) * W + o] = acc;
    }
}

// ---------------- pairwise: v_r[b,j,i], u_x[b,j,i]=exp(-x_r), atomicMax v_r_max
__global__ __launch_bounds__(256) void k_pair(const float* __restrict__ pT,
                                              const float* __restrict__ aT,
                                              float* __restrict__ vr,
                                              float* __restrict__ uxm,
                                              unsigned* __restrict__ vmax) {
    int blk = blockIdx.x;
    int b = blk >> 8;
    int rest = blk & 255;
    int i0 = (rest & 15) * 32, j0 = (rest >> 4) * 32;
    int tid = threadIdx.x;
    int tx = tid & 15, ty = tid >> 4;
    __shared__ float Pi[64 * 33], Pj[64 * 33], Vi[64 * 33], Vj[64 * 33];
    for (int idx = tid; idx < 2048; idx += 256) {
        int k = idx >> 6, c = idx & 63;
        Pi[c * 33 + k] = pT[(b * S + i0 + k) * W + c];
        Pj[c * 33 + k] = pT[(b * S + j0 + k) * W + c];
        Vi[c * 33 + k] = aT[(b * S + i0 + k) * W + c];
        Vj[c * 33 + k] = aT[(b * S + j0 + k) * W + c];
    }
    __syncthreads();
    float ax[2][2] = {{0.f, 0.f}, {0.f, 0.f}};
    float av[2][2] = {{0.f, 0.f}, {0.f, 0.f}};
    for (int c = 0; c < W; ++c) {
        float pi0 = Pi[c * 33 + 2 * tx], pi1 = Pi[c * 33 + 2 * tx + 1];
        float pj0 = Pj[c * 33 + 2 * ty], pj1 = Pj[c * 33 + 2 * ty + 1];
        float vi0 = Vi[c * 33 + 2 * tx], vi1 = Vi[c * 33 + 2 * tx + 1];
        float vj0 = Vj[c * 33 + 2 * ty], vj1 = Vj[c * 33 + 2 * ty + 1];
        float d;
        d = pi0 - pj0; ax[0][0] = fmaf(d, d, ax[0][0]);
        d = pi1 - pj0; ax[1][0] = fmaf(d, d, ax[1][0]);
        d = pi0 - pj1; ax[0][1] = fmaf(d, d, ax[0][1]);
        d = pi1 - pj1; ax[1][1] = fmaf(d, d, ax[1][1]);
        d = vi0 - vj0; av[0][0] = fmaf(d, d, av[0][0]);
        d = vi1 - vj0; av[1][0] = fmaf(d, d, av[1][0]);
        d = vi0 - vj1; av[0][1] = fmaf(d, d, av[0][1]);
        d = vi1 - vj1; av[1][1] = fmaf(d, d, av[1][1]);
    }
    float mx = 0.f;
#pragma unroll
    for (int jj = 0; jj < 2; ++jj) {
#pragma unroll
        for (int ii = 0; ii < 2; ++ii) {
            int i = i0 + 2 * tx + ii, j = j0 + 2 * ty + jj;
            float xr = sqrtf(ax[ii][jj]);
            float vv = sqrtf(av[ii][jj]);
            vr[((size_t)b * S + j) * S + i] = vv;
            uxm[((size_t)b * S + j) * S + i] = expf(-xr);
            mx = fmaxf(mx, vv);
        }
    }
    for (int off = 32; off; off >>= 1) mx = fmaxf(mx, __shfl_xor(mx, off));
    if ((tid & 63) == 0) atomicMax(&vmax[b], __float_as_uint(mx));
}

// ---------------- dsmc: block per (b,j), 256 thr. Compact active partners,
// then coalesced channel sums + pair-list gather of rvec.
__global__ __launch_bounds__(256) void k_dsmc2(const float* __restrict__ pT,
                                               const float* __restrict__ aT,
                                               const float* __restrict__ vr,
                                               const float* __restrict__ uxm,
                                               const unsigned* __restrict__ vmaxu,
                                               const float* __restrict__ vecs,
                                               float* __restrict__ h_std,
                                               float* __restrict__ hT,
                                               int l, int do_relu) {
    int b = blockIdx.x >> 9;
    int j = blockIdx.x & 511;
    int tid = threadIdx.x, lane = tid & 63, wv = tid >> 6;
    __shared__ float vrow[S], urow[S];
    __shared__ int idxl[S];
    __shared__ float wl[S];
    __shared__ int pl[S];
    __shared__ int wcnt[4];
    __shared__ float SVp[4][64], SXp[4][64];
    __shared__ float Tsh[64];
    const float* vrp = vr + ((size_t)b * S + j) * S;
    const float* uxp = uxm + ((size_t)b * S + j) * S;
    for (int i = tid; i < S; i += 256) { vrow[i] = vrp[i]; urow[i] = uxp[i]; }
    __syncthreads();
    float vmax = __uint_as_float(vmaxu[b]);
    // phase 1: ordered compaction. wave wv owns i in [wv*128, wv*128+128)
    int i1 = wv * 128 + lane, i2 = i1 + 64;
    bool a1 = (vrow[i1] / vmax) * urow[i1] > 0.1f;
    bool a2 = (vrow[i2] / vmax) * urow[i2] > 0.1f;
    unsigned long long m1 = __ballot(a1), m2 = __ballot(a2);
    int c1 = (int)__popcll(m1), c2 = (int)__popcll(m2);
    if (lane == 0) wcnt[wv] = c1 + c2;
    __syncthreads();
    int off = 0;
    for (int w = 0; w < wv; ++w) off += wcnt[w];
    int A = wcnt[0] + wcnt[1] + wcnt[2] + wcnt[3];
    unsigned long long bel = (1ull << lane) - 1ull;
    if (a1) {
        int pos = off + (int)__popcll(m1 & bel);
        int i = i1;
        idxl[pos] = i;
        wl[pos] = ((i < j) ? 1.0f : -1.0f) * vrow[i];
        int lo = (i < j) ? i : j, hi = (i < j) ? j : i;
        pl[pos] = lo * 511 - ((lo * (lo - 1)) >> 1) + (hi - lo - 1);
    }
    if (a2) {
        int pos = off + c1 + (int)__popcll(m2 & bel);
        int i = i2;
        idxl[pos] = i;
        wl[pos] = ((i < j) ? 1.0f : -1.0f) * vrow[i];
        int lo = (i < j) ? i : j, hi = (i < j) ? j : i;
        pl[pos] = lo * 511 - ((lo * (lo - 1)) >> 1) + (hi - lo - 1);
    }
    __syncthreads();
    // phase 2: partner channel sums, lanes over channels (coalesced)
    float sv = 0.f, sx = 0.f;
    for (int k = wv; k < A; k += 4) {
        int i = idxl[k];
        sv += aT[((size_t)b * S + i) * W + lane];
        sx += pT[((size_t)b * S + i) * W + lane];
    }
    SVp[wv][lane] = sv;
    SXp[wv][lane] = sx;
    // phase 3: T[c] = sum_k wl[k] * R[c, pl[k]], lanes over pair list
    const float* Rb = vecs + (size_t)((l * 2 + b) * W) * PAIRS;
    for (int cc = 0; cc < 16; ++cc) {
        int c = wv * 16 + cc;
        const float* Rc = Rb + (size_t)c * PAIRS;
        float t = 0.f;
        for (int k = lane; k < A; k += 64) t += wl[k] * Rc[pl[k]];
        for (int o2 = 32; o2; o2 >>= 1) t += __shfl_down(t, o2);
        if (lane == 0) Tsh[c] = t;
    }
    __syncthreads();
    if (tid < 64) {
        int c = tid;
        float svt = SVp[0][c] + SVp[1][c] + SVp[2][c] + SVp[3][c];
        float sxt = SXp[0][c] + SXp[1][c] + SXp[2][c] + SXp[3][c];
        float vj = aT[((size_t)b * S + j) * W + c];
        float xj = pT[((size_t)b * S + j) * W + c];
        float vnew = vj + 0.5f * ((float)A * vj - svt) + Tsh[c];
        float accx = 0.5f * ((float)A * xj + sxt);
        float xnew = (xj + accx) / (float)(A + 1) + vnew;
        if (do_relu) xnew = fmaxf(xnew, 0.0f);
        hT[((size_t)b * S + j) * W + c] = xnew;
        h_std[((size_t)b * W + c) * S + j] = xnew;
    }
}

// ---------------- head: out[b,t] = relu(hT[b,t,:]@fc1 + b1) @ fc2 + b2
__global__ __launch_bounds__(128) void k_head(const float* __restrict__ hT,
                                              const float* __restrict__ fc1w,
                                              const float* __restrict__ fc1b,
                                              const float* __restrict__ fc2w,
                                              const float* __restrict__ fc2b,
                                              float* __restrict__ out) {
    int blk = blockIdx.x;
    int b = blk >> 9, t = blk & 511;
    int k = threadIdx.x;  // 0..127
    __shared__ float hsh[64];
    __shared__ float red[2];
    if (k < 64) hsh[k] = hT[(b * S + t) * W + k];
    __syncthreads();
    float acc = fc1b[k];
#pragma unroll
    for (int c = 0; c < W; ++c) acc = fmaf(hsh[c], fc1w[c * 128 + k], acc);
    acc = fmaxf(acc, 0.f);
    float p = acc * fc2w[k];
    for (int off = 32; off; off >>= 1) p += __shfl_down(p, off);
    int lane = k & 63, wv = k >> 6;
    if (lane == 0) red[wv] = p;
    __syncthreads();
    if (k == 0) out[b * S + t] = red[0] + red[1] + fc2b[0];
}

extern "C" void kernel_launch(void* const* d_in, const int* in_sizes, int n_in,
                              void* d_out, int out_size, void* d_ws, size_t ws_size,
                              hipStream_t stream) {
    const float* x = (const float*)d_in[0];
    const float* vecs = (const float*)d_in[2];
    const float* fc0w = (const float*)d_in[3];
    const float* fc0b = (const float*)d_in[4];
    const float* specw = (const float*)d_in[5];
    const float* convw = (const float*)d_in[6];
    const float* convb = (const float*)d_in[7];
    const float* fc1w = (const float*)d_in[8];
    const float* fc1b = (const float*)d_in[9];
    const float* fc2w = (const float*)d_in[10];
    const float* fc2b = (const float*)d_in[11];
    float* out = (float*)d_out;

    char* ws = (char*)d_ws;
    unsigned* vmax = (unsigned*)ws;                   // 2 x u32 (float bits)
    float* h_std = (float*)(ws + 256);                // 2*64*512
    float* hT = h_std + 65536;                        // 2*512*64
    float* aT = hT + 65536;                           // 2*512*64
    float* pT = aT + 65536;                           // 2*512*64
    float* Xf = pT + 65536;                           // 2*64*16*2
    float* Yb = Xf + 4096;                            // 2*64*16*2
    float* vrbuf = Yb + 4096;                         // 2*512*512
    float* uxbuf = vrbuf + 524288;                    // 2*512*512

    k_fc0<<<128, 256, 0, stream>>>(x, fc0w, fc0b, h_std);
    for (int l = 0; l < 4; ++l) {
        k_fft<<<128, 256, 0, stream>>>(h_std, Xf);
        k_mix<<<128, 256, 0, stream>>>(Xf, specw, Yb, l);
        k_irfft<<<32, 256, 0, stream>>>(Yb, aT);
        k_conv<<<32, 256, 0, stream>>>(h_std, convw, convb, pT, vmax, l);
        k_pair<<<512, 256, 0, stream>>>(pT, aT, vrbuf, uxbuf, vmax);
        k_dsmc2<<<1024, 256, 0, stream>>>(pT, aT, vrbuf, uxbuf, vmax, vecs,
                                          h_std, hT, l, (l < 3) ? 1 : 0);
    }
    k_head<<<1024, 128, 0, stream>>>(hT, fc1w, fc1b, fc2w, fc2b, out);
}